// Round 7
// baseline (172.380 us; speedup 1.0000x reference)
//
#include <hip/hip_runtime.h>
#include <math.h>

// Problem constants
#define D 64
#define K 512
#define NROWS 65536
#define DECAY 0.99f
#define OMD (1.0f - 0.99f)
#define COMMIT 0.25f
#define DELTA 3.0e-3f            // rescue threshold >= 2x worst-case split-bf16 err

// ws float offsets
#define WS_DWT    0              // [K][D] dw accumulator
#define WS_COUNTS 32768          // [K]
#define WS_LOSS   33280          // [1]
#define WS_ESQ    33344          // [K] ||e_k||^2
#define WS_ET     33856          // [K][D] embeddings transposed (fp32)
#define WS_BSPLIT 66624          // 32768 bf16 (=16384 floats): frag-linear split codebook
#define WS_ZERO_FLOATS 33344

// out float offsets
#define OUT_Q     0
#define OUT_LOSS  4194304
#define OUT_PERP  4194305
#define OUT_IDX   4194306
#define OUT_NEMB  4259842
#define OUT_HCS   4292610
#define OUT_HDW   4293122

typedef __attribute__((ext_vector_type(8))) short short8;
typedef __attribute__((ext_vector_type(4))) float f32x4;

__device__ __forceinline__ unsigned short f2bf(float f) {   // RNE fp32->bf16
    unsigned u = __float_as_uint(f);
    u += 0x7fff + ((u >> 16) & 1);
    return (unsigned short)(u >> 16);
}
__device__ __forceinline__ float bf2f(unsigned short h) {
    return __uint_as_float(((unsigned)h) << 16);
}

// ---------------- prep: zero accum + e_t + esq + frag-linear split codebook --
// Bsplit layout (bf16): [chunk c(4)][set(32)][lane(64)][j(8)], set=(hl*2+t)*8+ct
// element value = split_hl(emb[k][col]) with col=c*128+ct*16+(lane&15),
// k = t*32 + (lane>>4)*8 + j  -> matches mfma_16x16x32_bf16 B-frag layout.
__global__ void vq_prep(const float* __restrict__ emb, float* __restrict__ ws)
{
    int i = blockIdx.x * 256 + threadIdx.x;    // 0..32767 (128 blocks)
    if (i < WS_ZERO_FLOATS / 4)
        ((float4*)ws)[i] = make_float4(0.f, 0.f, 0.f, 0.f);
    {   // e_t[k][d] = emb[d][k]
        int k = i >> 6, d = i & 63;
        ws[WS_ET + i] = emb[d * K + k];
    }
    {   // split codebook
        int col = i & 511, k = i >> 9;
        float v = emb[k * K + col];
        unsigned short h = f2bf(v);
        unsigned short l = f2bf(v - bf2f(h));
        short* bs = (short*)(ws + WS_BSPLIT);
        int c = col >> 7, ct = (col >> 4) & 7;
        int ln = (col & 15) | (((k >> 3) & 3) << 4);
        int t = k >> 5, j = k & 7;
        int base = ((c * 32 + t * 8 + ct) * 64 + ln) * 8 + j;  // hl=0
        bs[base] = (short)h;
        bs[base + 8192] = (short)l;                            // hl=1 (+16 sets)
    }
    if (i < K) {
        float s = 0.f;
        for (int d = 0; d < D; ++d) { float v = emb[d * K + i]; s += v * v; }
        ws[WS_ESQ + i] = s;
    }
}

// ---------------- main: split-bf16 MFMA distances + argmin + rescue + tail ---
__global__ __launch_bounds__(256, 2)
void vq_main(const float* __restrict__ x,      // [N][D]
             const float* __restrict__ emb,    // [D][K] (fp32, for rescue)
             const float* __restrict__ e_sq,   // [K]
             const float* __restrict__ e_t,    // [K][D]
             const short* __restrict__ bsplit, // frag-linear split codebook
             float* __restrict__ out_q,
             float* __restrict__ out_idx,
             float* __restrict__ dw_t,
             float* __restrict__ counts,
             float* __restrict__ loss_sum)
{
    __shared__ __align__(16) short Bsh[16384];  // 32KB: B-frags (or fp32 rescue chunk)
    __shared__ __align__(16) short Ash[8192];   // 16KB: A-frags (xh/xl)
    __shared__ __align__(16) float xs[4096];    // 16KB: fp32 x tile [row][d]
    __shared__ __align__(16) float esq_s[512];
    __shared__ int   idx_s[64];
    __shared__ int   flag_s[64];
    __shared__ int   list_s[64];
    __shared__ float rb_s[64];
    __shared__ int   rbk_s[64];
    __shared__ float red_s[4];
    __shared__ int   nflag_s;

    const int tid  = threadIdx.x;
    const int lane = tid & 63;
    const int wv   = tid >> 6;               // wave 0..3 -> rows wv*16..wv*16+15
    const int row0 = blockIdx.x * 64;

    // prefetch B chunk 0 (contiguous frag-linear copy)
    const float4* Bs4 = (const float4*)bsplit;
    float4 bpf[8];
#pragma unroll
    for (int t = 0; t < 8; ++t) bpf[t] = Bs4[tid + t * 256];

    if (tid < 128)
        *(float4*)&esq_s[tid * 4] = *(const float4*)&e_sq[tid * 4];

    // stage x: fp32 tile + bf16 hi/lo A-frags
    const float4* xin4 = (const float4*)x;
#pragma unroll
    for (int t = 0; t < 4; ++t) {
        int i = tid + t * 256;               // 0..1023 float4s of 64x64 tile
        int row = i >> 4, seg = i & 15;
        float4 v = xin4[(size_t)row0 * 16 + i];
        *(float4*)&xs[row * D + seg * 4] = v;
        int d0 = seg * 4;
        int tt = d0 >> 5;                    // k-tile 0/1
        int ln = (row & 15) | (((d0 >> 3) & 3) << 4);
        int w  = row >> 4;
        int j0 = d0 & 7;                     // 0 or 4
        unsigned short h0 = f2bf(v.x), h1 = f2bf(v.y), h2 = f2bf(v.z), h3 = f2bf(v.w);
        unsigned short l0 = f2bf(v.x - bf2f(h0)), l1 = f2bf(v.y - bf2f(h1));
        unsigned short l2 = f2bf(v.z - bf2f(h2)), l3 = f2bf(v.w - bf2f(h3));
        int base = ((w * 2 + tt) * 64 + ln) * 8 + j0;          // hl=0
        uint2 hp, lp;
        hp.x = (unsigned)h0 | ((unsigned)h1 << 16);
        hp.y = (unsigned)h2 | ((unsigned)h3 << 16);
        lp.x = (unsigned)l0 | ((unsigned)l1 << 16);
        lp.y = (unsigned)l2 | ((unsigned)l3 << 16);
        *(uint2*)&Ash[base] = hp;
        *(uint2*)&Ash[base + 4096] = lp;                       // hl=1 (+8 sets)
    }

    short8 ah0, ah1, al0, al1;
    float s1r[4], s2r[4]; int k1r[4];
#pragma unroll
    for (int r = 0; r < 4; ++r) { s1r[r] = 3.0e38f; s2r[r] = 3.0e38f; k1r[r] = 0; }

    for (int c = 0; c < 4; ++c) {
        __syncthreads();                      // Bsh consumers done / staging done
        float4* Bf4 = (float4*)Bsh;
#pragma unroll
        for (int t = 0; t < 8; ++t) Bf4[tid + t * 256] = bpf[t];
        __syncthreads();
        if (c == 0) {                         // A-frags once (persist in regs)
            ah0 = *(const short8*)&Ash[((wv * 2 + 0) * 64 + lane) * 8];
            ah1 = *(const short8*)&Ash[((wv * 2 + 1) * 64 + lane) * 8];
            al0 = *(const short8*)&Ash[((8 + wv * 2 + 0) * 64 + lane) * 8];
            al1 = *(const short8*)&Ash[((8 + wv * 2 + 1) * 64 + lane) * 8];
        }
        if (c < 3) {                          // prefetch next chunk (hidden)
#pragma unroll
            for (int t = 0; t < 8; ++t)
                bpf[t] = Bs4[(c + 1) * 2048 + tid + t * 256];
        }
#pragma unroll
        for (int ct = 0; ct < 8; ++ct) {
            short8 bh0 = *(const short8*)&Bsh[((ct)      * 64 + lane) * 8];
            short8 bh1 = *(const short8*)&Bsh[((8 + ct)  * 64 + lane) * 8];
            short8 bl0 = *(const short8*)&Bsh[((16 + ct) * 64 + lane) * 8];
            short8 bl1 = *(const short8*)&Bsh[((24 + ct) * 64 + lane) * 8];
            f32x4 acc = {0.f, 0.f, 0.f, 0.f};
            acc = __builtin_amdgcn_mfma_f32_16x16x32_bf16(ah0, bh0, acc, 0, 0, 0);
            acc = __builtin_amdgcn_mfma_f32_16x16x32_bf16(ah1, bh1, acc, 0, 0, 0);
            acc = __builtin_amdgcn_mfma_f32_16x16x32_bf16(ah0, bl0, acc, 0, 0, 0);
            acc = __builtin_amdgcn_mfma_f32_16x16x32_bf16(ah1, bl1, acc, 0, 0, 0);
            acc = __builtin_amdgcn_mfma_f32_16x16x32_bf16(al0, bh0, acc, 0, 0, 0);
            acc = __builtin_amdgcn_mfma_f32_16x16x32_bf16(al1, bh1, acc, 0, 0, 0);
            int col = c * 128 + ct * 16 + (lane & 15);
            float sq = esq_s[col];
#pragma unroll
            for (int r = 0; r < 4; ++r) {     // C/D: col=lane&15, row=quad*4+r
                float s = sq - 2.0f * acc[r];
                if (s < s1r[r]) { s2r[r] = s1r[r]; s1r[r] = s; k1r[r] = col; }
                else if (s < s2r[r]) { s2r[r] = s; }
            }
        }
    }

    // top-2 merge across the 16 lanes holding the same rows (quad groups)
#pragma unroll
    for (int r = 0; r < 4; ++r) {
        float a1 = s1r[r], a2 = s2r[r]; int ak = k1r[r];
        for (int m = 1; m <= 8; m <<= 1) {
            float o1 = __shfl_xor(a1, m, 64);
            int   ok = __shfl_xor(ak, m, 64);
            float o2 = __shfl_xor(a2, m, 64);
            bool take = (o1 < a1) || (o1 == a1 && ok < ak);
            float big = take ? a1 : o1;
            a1 = take ? o1 : a1;
            ak = take ? ok : ak;
            a2 = fminf(big, fminf(a2, o2));
        }
        if ((lane & 15) == 0) {
            int rl = wv * 16 + (lane >> 4) * 4 + r;
            idx_s[rl]  = ak;
            flag_s[rl] = (a2 - a1 < DELTA) ? 1 : 0;
        }
    }

    // ---- exact fp32 rescue for ambiguous rows (block-cooperative) ----
    if (tid == 0) nflag_s = 0;
    __syncthreads();
    if (tid < 64) {
        rb_s[tid] = 3.0e38f; rbk_s[tid] = 0;
        if (flag_s[tid]) { int p = atomicAdd(&nflag_s, 1); list_s[p] = tid; }
    }
    __syncthreads();
    const int nf = nflag_s;                   // block-uniform
    if (nf > 0) {
        float* es32 = (float*)Bsh;            // reuse B region: 64x128 fp32
        const float4* emb4 = (const float4*)emb;
        for (int c = 0; c < 4; ++c) {
            __syncthreads();
            float4* es4 = (float4*)es32;
#pragma unroll
            for (int t = 0; t < 8; ++t) {
                int f = tid + t * 256;        // 0..2047
                int d = f >> 5, j4 = f & 31;
                es4[d * 32 + j4] = emb4[d * 128 + c * 32 + j4];
            }
            __syncthreads();
            for (int fi = wv; fi < nf; fi += 4) {   // one wave per flagged row
                int row = list_s[fi];
                float b1 = rb_s[fi]; int bk = rbk_s[fi];
#pragma unroll
                for (int h = 0; h < 2; ++h) {
                    int j = lane * 2 + h;
                    float dot = 0.f;
#pragma unroll 8
                    for (int d = 0; d < 64; ++d)
                        dot = fmaf(xs[row * 64 + d], es32[d * 128 + j], dot);
                    int col = c * 128 + j;
                    float s = esq_s[col] - 2.0f * dot;
                    if (s < b1 || (s == b1 && col < bk)) { b1 = s; bk = col; }
                }
                for (int m = 1; m <= 32; m <<= 1) {
                    float ob = __shfl_xor(b1, m, 64);
                    int  obk = __shfl_xor(bk, m, 64);
                    if (ob < b1 || (ob == b1 && obk < bk)) { b1 = ob; bk = obk; }
                }
                if (lane == 0) { rb_s[fi] = b1; rbk_s[fi] = bk; }
            }
        }
        __syncthreads();
        if (tid < nf) idx_s[list_s[tid]] = rbk_s[tid];
        __syncthreads();
    }

    // ---- epilogue: gather/out_q/loss/counts/dw ----
    float lsum = 0.f;
    for (int i = tid * 4; i < 64 * D; i += 1024) {
        int r = i >> 6, d = i & 63;
        int kk = idx_s[r];
        float4 q  = *(const float4*)&e_t[kk * D + d];
        float4 xv = *(const float4*)&xs[r * D + d];
        float d0 = q.x - xv.x, d1 = q.y - xv.y, d2 = q.z - xv.z, d3 = q.w - xv.w;
        lsum += d0 * d0 + d1 * d1 + d2 * d2 + d3 * d3;
        *(float4*)&out_q[(size_t)(row0 + r) * D + d] = q;
    }
    for (int m = 32; m >= 1; m >>= 1) lsum += __shfl_xor(lsum, m, 64);
    if (lane == 0) red_s[wv] = lsum;
    __syncthreads();
    if (tid == 0)
        atomicAdd(loss_sum, red_s[0] + red_s[1] + red_s[2] + red_s[3]);

    if (tid < 64) {
        int kk = idx_s[tid];
        out_idx[row0 + tid] = (float)kk;
        atomicAdd(&counts[kk], 1.0f);
    }
    for (int i = tid; i < 64 * D; i += 256) {   // wave sweeps one row: coalesced
        int r = i >> 6, d = i & 63;
        atomicAdd(&dw_t[idx_s[r] * D + d], xs[r * D + d]);
    }
}

// ---------------- finalize (merged): EMA, debias, perplexity, new emb --------
__global__ void vq_final(const float* __restrict__ counts,
                         const float* __restrict__ dw_t,     // [K][D]
                         const float* __restrict__ loss_sum,
                         const float* __restrict__ ema_csh,  // [K]
                         const float* __restrict__ ema_dwh,  // [D][K]
                         const int*   __restrict__ counter,
                         float* __restrict__ out_loss,
                         float* __restrict__ out_perp,
                         float* __restrict__ out_hcs,        // [K]
                         float* __restrict__ out_nemb,       // [D][K]
                         float* __restrict__ out_hdw)        // [D][K]
{
    __shared__ float pn[4], pe[4];
    const int tid = threadIdx.x, lane = tid & 63, wvv = tid >> 6;
    const int cnt = counter[0] + 1;
    const float debias = 1.0f - powf(DECAY, (float)cnt);

    float a = 0.f, b = 0.f;                  // every block computes n/ent (cheap)
#pragma unroll
    for (int h = 0; h < 2; ++h) {
        int k = tid * 2 + h;
        float cc  = counts[k];
        float hid = ema_csh[k] * DECAY + cc * OMD;
        a += hid / debias;
        float p = cc * (1.0f / (float)NROWS);
        b += p * logf(p + 1e-10f);
        if (blockIdx.x == 0) out_hcs[k] = hid;
    }
    for (int m = 32; m >= 1; m >>= 1) { a += __shfl_xor(a, m, 64); b += __shfl_xor(b, m, 64); }
    if (lane == 0) { pn[wvv] = a; pe[wvv] = b; }
    __syncthreads();
    float n   = pn[0] + pn[1] + pn[2] + pn[3];
    float ent = pe[0] + pe[1] + pe[2] + pe[3];

    int i = blockIdx.x * 256 + tid;          // 0..32767 over [D][K]
    int d = i >> 9, kk = i & 511;
    float hidk   = ema_csh[kk] * DECAY + counts[kk] * OMD;
    float updk   = hidk / debias;
    float stable = (updk + 1e-5f) / (n + (float)K * 1e-5f) * n;
    float hdw    = ema_dwh[i] * DECAY + dw_t[kk * D + d] * OMD;
    out_hdw[i]  = hdw;
    out_nemb[i] = (hdw / debias) / stable;

    if (blockIdx.x == 0 && tid == 0) {
        out_loss[0] = COMMIT * loss_sum[0] / (float)((size_t)NROWS * D);
        out_perp[0] = expf(-ent);
    }
}

// ---------------- launch ------------------------------------------------------
extern "C" void kernel_launch(void* const* d_in, const int* in_sizes, int n_in,
                              void* d_out, int out_size, void* d_ws, size_t ws_size,
                              hipStream_t stream)
{
    const float* x_in    = (const float*)d_in[0];
    const float* emb     = (const float*)d_in[1];
    const float* ema_csh = (const float*)d_in[2];
    const float* ema_dwh = (const float*)d_in[3];
    const int*   counter = (const int*)d_in[4];

    float* ws  = (float*)d_ws;
    float* out = (float*)d_out;

    vq_prep<<<128, 256, 0, stream>>>(emb, ws);

    vq_main<<<NROWS / 64, 256, 0, stream>>>(
        x_in, emb, ws + WS_ESQ, ws + WS_ET, (const short*)(ws + WS_BSPLIT),
        out + OUT_Q, out + OUT_IDX,
        ws + WS_DWT, ws + WS_COUNTS, ws + WS_LOSS);

    vq_final<<<128, 256, 0, stream>>>(
        ws + WS_COUNTS, ws + WS_DWT, ws + WS_LOSS, ema_csh, ema_dwh, counter,
        out + OUT_LOSS, out + OUT_PERP, out + OUT_HCS,
        out + OUT_NEMB, out + OUT_HDW);
}